// Round 4
// baseline (749.299 us; speedup 1.0000x reference)
//
#include <hip/hip_runtime.h>

#define CC   192
#define HH   128
#define WWD  128
#define HW   16384
#define CHWs (CC * HW)

typedef __attribute__((ext_vector_type(4))) float f4;
typedef __attribute__((ext_vector_type(4))) float f32x4;
typedef __attribute__((ext_vector_type(8))) short bf16x8;

static __device__ __forceinline__ unsigned short f2bf(float f) {
    unsigned u = __float_as_uint(f);
    u += 0x7fffu + ((u >> 16) & 1u);     // RNE to bf16
    return (unsigned short)(u >> 16);
}
static __device__ __forceinline__ float bf2f(unsigned short h) {
    return __uint_as_float(((unsigned)h) << 16);
}

// ---- prep: split W (192x192 f32) into bf16 hi/lo planes in d_ws ----------
extern "C" __global__ __launch_bounds__(256)
void wsplit_kernel(const float* __restrict__ wm,
                   unsigned short* __restrict__ whi,
                   unsigned short* __restrict__ wlo)
{
    int i = blockIdx.x * 256 + threadIdx.x;
    if (i < CC * CC) {
        float f = wm[i];
        unsigned short h = f2bf(f);
        float l = f - bf2f(h);
        whi[i] = h;
        wlo[i] = (unsigned short)(__float_as_uint(l) >> 16);  // trunc ok for lo
    }
}

// WG = (image, 2-row strip). Output tile M=192 x N=256 px.
// 8 waves: 4(M) x 2(N). Per wave: 48 x 128 -> acc f32x4[3][8].
// K-loop: 6 chunks of 32 channels, double-buffered T in LDS (one barrier per
// chunk; x prefetch issued AFTER the barrier so it stays in flight over the
// MFMA phase and drains naturally at STENCIL — never at a barrier).
extern "C" __global__ __launch_bounds__(512, 4)
void eeb_kernel(const float* __restrict__ x,
                const unsigned short* __restrict__ whi,
                const unsigned short* __restrict__ wlo,
                const float* __restrict__ bias, float* __restrict__ y)
{
    __shared__ __align__(16) char Tl[2][2][16384];  // [buf][hi/lo][256px*64B]

    const int tid = threadIdx.x;
    const int bid = blockIdx.x;
    const int img = bid >> 6;
    const int r0  = (bid & 63) << 1;

    // ---- producer ids: thread = (channel pair, 8-px span)
    const int cp = tid >> 5;            // 0..15
    const int sp = tid & 31;            // 0..31
    const int p0 = sp << 3;             // 0..248
    const int w0 = p0 & 127;
    const int rr = r0 + (p0 >> 7);      // image row of this span
    const bool upv = (rr > 0), dnv = (rr < 127);
    const int rup = upv ? rr - 1 : rr;  // clamped (never OOB)
    const int rdn = dnv ? rr + 1 : rr;

    // ---- consumer ids
    const int lane = tid & 63;
    const int wid  = tid >> 6;
    const int mb = (wid >> 1) * 48;     // wave M base
    const int nb = (wid & 1) * 128;     // wave N base
    const int lr = lane & 15;
    const int lg = lane >> 4;

    const float* xb = x + (size_t)img * CHWs;

    f32x4 acc[3][8];
    #pragma unroll
    for (int i = 0; i < 3; ++i)
        #pragma unroll
        for (int j = 0; j < 8; ++j) acc[i][j] = f32x4{0.f, 0.f, 0.f, 0.f};

    f4 xm[2][2], xu[2][2], xd[2][2];    // in-flight x tiles (2 ch x 3 rows x 8 w)
    float tv[2][8];                     // stencil results

    auto LOADX = [&](int kc) {
        #pragma unroll
        for (int ch = 0; ch < 2; ++ch) {
            const float* cb = xb + (size_t)(kc + 2 * cp + ch) * HW;
            const f4* pm = (const f4*)(cb + rr  * WWD + w0);
            const f4* pu = (const f4*)(cb + rup * WWD + w0);
            const f4* pd = (const f4*)(cb + rdn * WWD + w0);
            xm[ch][0] = pm[0]; xm[ch][1] = pm[1];
            xu[ch][0] = pu[0]; xu[ch][1] = pu[1];
            xd[ch][0] = pd[0]; xd[ch][1] = pd[1];
        }
    };
    auto STENCIL = [&]() {
        #pragma unroll
        for (int ch = 0; ch < 2; ++ch) {
            float mm[8], uu[8], dd[8];
            #pragma unroll
            for (int i = 0; i < 8; ++i) {
                mm[i] = xm[ch][i >> 2][i & 3];
                uu[i] = upv ? xu[ch][i >> 2][i & 3] : 0.f;
                dd[i] = dnv ? xd[ch][i >> 2][i & 3] : 0.f;
            }
            float lft = __shfl_up(mm[7], 1);    // lane-1's w0+7  == our w0-1
            float rgt = __shfl_down(mm[0], 1);  // lane+1's w0    == our w0+8
            if (w0 == 0)   lft = 0.f;           // image left edge
            if (w0 == 120) rgt = 0.f;           // image right edge
            tv[ch][0] = 5.f * mm[0] - uu[0] - dd[0] - lft - mm[1];
            #pragma unroll
            for (int i = 1; i < 7; ++i)
                tv[ch][i] = 5.f * mm[i] - uu[i] - dd[i] - mm[i - 1] - mm[i + 1];
            tv[ch][7] = 5.f * mm[7] - uu[7] - dd[7] - mm[6] - rgt;
        }
    };

    LOADX(0);
    STENCIL();

    #pragma unroll 1
    for (int kb = 0; kb < 6; ++kb) {
        const int kc = kb * 32;
        char* Tw = &Tl[kb & 1][0][0];
        // ---- write T (bf16 hi/lo, packed 2 channels per b32, swizzled)
        #pragma unroll
        for (int i = 0; i < 8; ++i) {
            const int p   = p0 + i;
            const int off = (4 * cp) ^ ((((unsigned)p >> 4) & 3) << 4);
            unsigned short h0 = f2bf(tv[0][i]);
            unsigned short h1 = f2bf(tv[1][i]);
            unsigned short l0 = (unsigned short)(__float_as_uint(tv[0][i] - bf2f(h0)) >> 16);
            unsigned short l1 = (unsigned short)(__float_as_uint(tv[1][i] - bf2f(h1)) >> 16);
            *(unsigned*)&Tw[p * 64 + off]         = (unsigned)h0 | ((unsigned)h1 << 16);
            *(unsigned*)&Tw[16384 + p * 64 + off] = (unsigned)l0 | ((unsigned)l1 << 16);
        }
        __syncthreads();                         // T[kb] visible; prev buf reads done
        if (kb < 5) LOADX(kc + 32);              // in flight across whole MFMA phase

        // ---- A fragments: preconverted bf16 hi/lo from d_ws (L2-resident)
        bf16x8 ah[3], al[3];
        #pragma unroll
        for (int mf = 0; mf < 3; ++mf) {
            const size_t wo = (size_t)(mb + mf * 16 + lr) * CC + kc + lg * 8;
            ah[mf] = *(const bf16x8*)(whi + wo);
            al[mf] = *(const bf16x8*)(wlo + wo);
        }
        // ---- MFMA: 8 n-frags x 3 m-frags x 3 split products
        #pragma unroll
        for (int nf = 0; nf < 8; ++nf) {
            const int pb  = nb + nf * 16;
            const int swz = ((pb >> 4) & 3) << 4;
            const char* rb = &Tw[(pb + lr) * 64 + ((16 * lg) ^ swz)];
            bf16x8 bh = *(const bf16x8*)rb;
            bf16x8 bl = *(const bf16x8*)(rb + 16384);
            #pragma unroll
            for (int mf = 0; mf < 3; ++mf) {
                acc[mf][nf] = __builtin_amdgcn_mfma_f32_16x16x32_bf16(ah[mf], bh, acc[mf][nf], 0, 0, 0);
                acc[mf][nf] = __builtin_amdgcn_mfma_f32_16x16x32_bf16(ah[mf], bl, acc[mf][nf], 0, 0, 0);
                acc[mf][nf] = __builtin_amdgcn_mfma_f32_16x16x32_bf16(al[mf], bh, acc[mf][nf], 0, 0, 0);
            }
        }
        if (kb < 5) STENCIL();                   // consumes in-flight x loads
    }

    // ---- epilogue: bias + store (C/D layout: row = 4*lg + r, col = lr)
    float bv[3][4];
    #pragma unroll
    for (int mf = 0; mf < 3; ++mf)
        #pragma unroll
        for (int r = 0; r < 4; ++r)
            bv[mf][r] = bias[mb + mf * 16 + lg * 4 + r];

    float* yb = y + (size_t)img * CHWs;
    #pragma unroll
    for (int mf = 0; mf < 3; ++mf) {
        #pragma unroll
        for (int nf = 0; nf < 8; ++nf) {
            const int p = nb + nf * 16 + lr;
            float* yp = yb + (size_t)(mb + mf * 16 + lg * 4) * HW
                           + (r0 + (p >> 7)) * WWD + (p & 127);
            #pragma unroll
            for (int r = 0; r < 4; ++r)
                yp[r * HW] = acc[mf][nf][r] + bv[mf][r];
        }
    }
}

extern "C" void kernel_launch(void* const* d_in, const int* in_sizes, int n_in,
                              void* d_out, int out_size, void* d_ws, size_t ws_size,
                              hipStream_t stream)
{
    const float* x  = (const float*)d_in[0];   // (16,192,128,128) f32
    const float* wm = (const float*)d_in[1];   // (192,192,1,1)    f32
    const float* b  = (const float*)d_in[2];   // (192,)           f32
    float* y = (float*)d_out;                  // (16,192,128,128) f32

    unsigned short* whi = (unsigned short*)d_ws;            // 192*192 bf16
    unsigned short* wlo = whi + CC * CC;                    // 192*192 bf16

    wsplit_kernel<<<(CC * CC + 255) / 256, 256, 0, stream>>>(wm, whi, wlo);
    eeb_kernel<<<1024, 512, 0, stream>>>(x, whi, wlo, b, y);
}

// Round 12
// 399.471 us; speedup vs baseline: 1.8757x; 1.8757x over previous
//
#include <hip/hip_runtime.h>

#define CC   192
#define HH   128
#define WWD  128
#define HW   16384
#define CHWs (CC * HW)

typedef __attribute__((ext_vector_type(4))) float f4;
typedef __attribute__((ext_vector_type(4))) float f32x4;
typedef __attribute__((ext_vector_type(8))) short bf16x8;

static __device__ __forceinline__ unsigned short f2bf(float f) {
    unsigned u = __float_as_uint(f);
    u += 0x7fffu + ((u >> 16) & 1u);     // RNE to bf16
    return (unsigned short)(u >> 16);
}
static __device__ __forceinline__ float bf2f(unsigned short h) {
    return __uint_as_float(((unsigned)h) << 16);
}

// ---- prep: split W (192x192 f32) into bf16 hi/lo planes in d_ws ----------
extern "C" __global__ __launch_bounds__(256)
void wsplit_kernel(const float* __restrict__ wm,
                   unsigned short* __restrict__ whi,
                   unsigned short* __restrict__ wlo)
{
    int i = blockIdx.x * 256 + threadIdx.x;
    if (i < CC * CC) {
        float f = wm[i];
        unsigned short h = f2bf(f);
        float l = f - bf2f(h);
        whi[i] = h;
        wlo[i] = (unsigned short)(__float_as_uint(l) >> 16);  // trunc ok for lo
    }
}

// WG = (image, 2-row strip). Output tile M=192 x N=256 px.
// 8 waves: 4(M) x 2(N). Per wave: 48 x 128 -> acc f32x4[3][8] (96 VGPR).
// launch_bounds(512,2): VGPR cap 256, compiler ~128, NO SPILL. (512,4) was
// measured R4: VGPR forced to 64 -> 1.14 GB spill writes, 515 us. Never again.
// K-loop: 6 chunks of 32 channels, double-buffered T in LDS (one barrier per
// chunk; x prefetch issued AFTER the barrier so it stays in flight over the
// MFMA phase and drains naturally at STENCIL — never at a barrier).
extern "C" __global__ __launch_bounds__(512, 2)
void eeb_kernel(const float* __restrict__ x,
                const unsigned short* __restrict__ whi,
                const unsigned short* __restrict__ wlo,
                const float* __restrict__ bias, float* __restrict__ y)
{
    __shared__ __align__(16) char Tl[2][2][16384];  // [buf][hi/lo][256px*64B]

    const int tid = threadIdx.x;
    const int bid = blockIdx.x;
    const int img = bid >> 6;
    const int r0  = (bid & 63) << 1;

    // ---- producer ids: thread = (channel pair, 8-px span)
    const int cp = tid >> 5;            // 0..15
    const int sp = tid & 31;            // 0..31
    const int p0 = sp << 3;             // 0..248
    const int w0 = p0 & 127;
    const int rr = r0 + (p0 >> 7);      // image row of this span
    const bool upv = (rr > 0), dnv = (rr < 127);
    const int rup = upv ? rr - 1 : rr;  // clamped (never OOB)
    const int rdn = dnv ? rr + 1 : rr;

    // ---- consumer ids
    const int lane = tid & 63;
    const int wid  = tid >> 6;
    const int mb = (wid >> 1) * 48;     // wave M base
    const int nb = (wid & 1) * 128;     // wave N base
    const int lr = lane & 15;
    const int lg = lane >> 4;

    const float* xb = x + (size_t)img * CHWs;

    f32x4 acc[3][8];
    #pragma unroll
    for (int i = 0; i < 3; ++i)
        #pragma unroll
        for (int j = 0; j < 8; ++j) acc[i][j] = f32x4{0.f, 0.f, 0.f, 0.f};

    f4 xm[2][2], xu[2][2], xd[2][2];    // in-flight x tiles (2 ch x 3 rows x 8 w)
    float tv[2][8];                     // stencil results

    auto LOADX = [&](int kc) {
        #pragma unroll
        for (int ch = 0; ch < 2; ++ch) {
            const float* cb = xb + (size_t)(kc + 2 * cp + ch) * HW;
            const f4* pm = (const f4*)(cb + rr  * WWD + w0);
            const f4* pu = (const f4*)(cb + rup * WWD + w0);
            const f4* pd = (const f4*)(cb + rdn * WWD + w0);
            xm[ch][0] = pm[0]; xm[ch][1] = pm[1];
            xu[ch][0] = pu[0]; xu[ch][1] = pu[1];
            xd[ch][0] = pd[0]; xd[ch][1] = pd[1];
        }
    };
    auto STENCIL = [&]() {
        #pragma unroll
        for (int ch = 0; ch < 2; ++ch) {
            float mm[8], uu[8], dd[8];
            #pragma unroll
            for (int i = 0; i < 8; ++i) {
                mm[i] = xm[ch][i >> 2][i & 3];
                uu[i] = upv ? xu[ch][i >> 2][i & 3] : 0.f;
                dd[i] = dnv ? xd[ch][i >> 2][i & 3] : 0.f;
            }
            float lft = __shfl_up(mm[7], 1);    // lane-1's w0+7  == our w0-1
            float rgt = __shfl_down(mm[0], 1);  // lane+1's w0    == our w0+8
            if (w0 == 0)   lft = 0.f;           // image left edge
            if (w0 == 120) rgt = 0.f;           // image right edge
            tv[ch][0] = 5.f * mm[0] - uu[0] - dd[0] - lft - mm[1];
            #pragma unroll
            for (int i = 1; i < 7; ++i)
                tv[ch][i] = 5.f * mm[i] - uu[i] - dd[i] - mm[i - 1] - mm[i + 1];
            tv[ch][7] = 5.f * mm[7] - uu[7] - dd[7] - mm[6] - rgt;
        }
    };

    LOADX(0);
    STENCIL();

    #pragma unroll 1
    for (int kb = 0; kb < 6; ++kb) {
        const int kc = kb * 32;
        char* Tw = &Tl[kb & 1][0][0];
        // ---- write T (bf16 hi/lo, packed 2 channels per b32, swizzled)
        #pragma unroll
        for (int i = 0; i < 8; ++i) {
            const int p   = p0 + i;
            const int off = (4 * cp) ^ ((((unsigned)p >> 4) & 3) << 4);
            unsigned short h0 = f2bf(tv[0][i]);
            unsigned short h1 = f2bf(tv[1][i]);
            unsigned short l0 = (unsigned short)(__float_as_uint(tv[0][i] - bf2f(h0)) >> 16);
            unsigned short l1 = (unsigned short)(__float_as_uint(tv[1][i] - bf2f(h1)) >> 16);
            *(unsigned*)&Tw[p * 64 + off]         = (unsigned)h0 | ((unsigned)h1 << 16);
            *(unsigned*)&Tw[16384 + p * 64 + off] = (unsigned)l0 | ((unsigned)l1 << 16);
        }
        __syncthreads();                         // T[kb] visible; prev buf reads done
        if (kb < 5) LOADX(kc + 32);              // in flight across whole MFMA phase

        // ---- A fragments: preconverted bf16 hi/lo from d_ws (L2-resident)
        bf16x8 ah[3], al[3];
        #pragma unroll
        for (int mf = 0; mf < 3; ++mf) {
            const size_t wo = (size_t)(mb + mf * 16 + lr) * CC + kc + lg * 8;
            ah[mf] = *(const bf16x8*)(whi + wo);
            al[mf] = *(const bf16x8*)(wlo + wo);
        }
        // ---- MFMA: 8 n-frags x 3 m-frags x 3 split products
        #pragma unroll
        for (int nf = 0; nf < 8; ++nf) {
            const int pb  = nb + nf * 16;
            const int swz = ((pb >> 4) & 3) << 4;
            const char* rb = &Tw[(pb + lr) * 64 + ((16 * lg) ^ swz)];
            bf16x8 bh = *(const bf16x8*)rb;
            bf16x8 bl = *(const bf16x8*)(rb + 16384);
            #pragma unroll
            for (int mf = 0; mf < 3; ++mf) {
                acc[mf][nf] = __builtin_amdgcn_mfma_f32_16x16x32_bf16(ah[mf], bh, acc[mf][nf], 0, 0, 0);
                acc[mf][nf] = __builtin_amdgcn_mfma_f32_16x16x32_bf16(ah[mf], bl, acc[mf][nf], 0, 0, 0);
                acc[mf][nf] = __builtin_amdgcn_mfma_f32_16x16x32_bf16(al[mf], bh, acc[mf][nf], 0, 0, 0);
            }
        }
        if (kb < 5) STENCIL();                   // consumes in-flight x loads
    }

    // ---- epilogue: bias + store (C/D layout: row = 4*lg + r, col = lr)
    float bv[3][4];
    #pragma unroll
    for (int mf = 0; mf < 3; ++mf)
        #pragma unroll
        for (int r = 0; r < 4; ++r)
            bv[mf][r] = bias[mb + mf * 16 + lg * 4 + r];

    float* yb = y + (size_t)img * CHWs;
    #pragma unroll
    for (int mf = 0; mf < 3; ++mf) {
        #pragma unroll
        for (int nf = 0; nf < 8; ++nf) {
            const int p = nb + nf * 16 + lr;
            float* yp = yb + (size_t)(mb + mf * 16 + lg * 4) * HW
                           + (r0 + (p >> 7)) * WWD + (p & 127);
            #pragma unroll
            for (int r = 0; r < 4; ++r)
                yp[r * HW] = acc[mf][nf][r] + bv[mf][r];
        }
    }
}

extern "C" void kernel_launch(void* const* d_in, const int* in_sizes, int n_in,
                              void* d_out, int out_size, void* d_ws, size_t ws_size,
                              hipStream_t stream)
{
    const float* x  = (const float*)d_in[0];   // (16,192,128,128) f32
    const float* wm = (const float*)d_in[1];   // (192,192,1,1)    f32
    const float* b  = (const float*)d_in[2];   // (192,)           f32
    float* y = (float*)d_out;                  // (16,192,128,128) f32

    unsigned short* whi = (unsigned short*)d_ws;            // 192*192 bf16
    unsigned short* wlo = whi + CC * CC;                    // 192*192 bf16

    wsplit_kernel<<<(CC * CC + 255) / 256, 256, 0, stream>>>(wm, whi, wlo);
    eeb_kernel<<<1024, 512, 0, stream>>>(x, whi, wlo, b, y);
}